// Round 16
// baseline (98.240 us; speedup 1.0000x reference)
//
#include <hip/hip_runtime.h>
#include <stdint.h>

#define Bdim 512
#define Tdim 2000
#define Ddim 20
#define Hdim 128
#define Cdim 10
#define TT   32
#define NCHF 62              // full 32-t chunks; chunk 62 = 16-t tail; phases 0..63
#define BETA 0.95f
#define THR  0.8f

typedef float f32x2 __attribute__((ext_vector_type(2)));
typedef float f32x4 __attribute__((ext_vector_type(4)));
typedef int   i32x4 __attribute__((ext_vector_type(4)));

// f32 pair -> packed bf16 hi + packed bf16 lo (RNE)
#define CVT_HILO(HI, LO, F0, F1) {                                                     \
    asm volatile("v_cvt_pk_bf16_f32 %0, %1, %2" : "=v"(HI) : "v"(F0), "v"(F1));        \
    const float h0f_ = __uint_as_float((HI) << 16);                                    \
    const float h1f_ = __uint_as_float((HI) & 0xFFFF0000u);                            \
    const float l0_ = (F0) - h0f_;  const float l1_ = (F1) - h1f_;                     \
    asm volatile("v_cvt_pk_bf16_f32 %0, %1, %2" : "=v"(LO) : "v"(l0_), "v"(l1_)); }

#define MFMA0(ACC, A8, B8) \
  asm volatile("v_mfma_f32_16x16x32_bf16 %0, %1, %2, 0"  : "=v"(ACC) : "v"(A8), "v"(B8));
#define MFMA(ACC, A8, B8)  \
  asm volatile("v_mfma_f32_16x16x32_bf16 %0, %1, %2, %0" : "+v"(ACC) : "v"(A8), "v"(B8));

__global__ __launch_bounds__(256, 1) void snn_spec5_kernel(
    const float* __restrict__ x,   // [B,T,D]
    const float* __restrict__ W1,  // [H,D]
    const float* __restrict__ b1,  // [H]
    const float* __restrict__ W2,  // [C,H]
    const float* __restrict__ b2,  // [C]
    float* __restrict__ out)       // [B,C] (pre-zeroed; atomic partial sums)
{
  const int blk = blockIdx.x;     // 0..1023
  const int bb  = blk >> 1;       // batch sample
  const int hh  = blk & 1;        // h-half: h in [hh*64, hh*64+64)
  const int tid = threadIdx.x;    // 0..255
  const int wid = tid >> 6;
  const int l   = tid & 63;
  const int r   = l & 15;
  const int g   = l >> 4;

  // Role flip by bit 8: co-resident blocks {c, c+256, c+512, c+768} give each
  // SIMD 2 producers + 2 scanners instead of 4 of one role.
  const bool flip = ((blk >> 8) & 1) != 0;
  const bool isP  = flip ? (wid >= 2) : (wid < 2);
  const int  pwid = wid & 1;      // producer 0/1: owns 16-t tile pwid
  const int  swid = wid & 1;      // scanner 0/1: owns cols [swid*32, swid*32+32)

  __shared__ __align__(16) float xraw[2][TT * Ddim];    // 2 x 2560 B
  __shared__ __align__(16) float cur[2][TT * 66];       // 2 x 8448 B, t-major stride 66 dw
  __shared__ float cnt_s[64];

  const float* xb = x + (size_t)bb * (Tdim * Ddim);
  const float* const clampMax = x + (size_t)Bdim * Tdim * Ddim - 4;

  const uint32_t xrawB = (uint32_t)(uintptr_t)&xraw[0][0];
  const uint32_t curB  = (uint32_t)(uintptr_t)&cur[0][0];

  // ---------------- producer-only setup: 4 ni covering this block's 64 h ----------------
  i32x4 bhi[4], blo[4];
  f32x4 zero4, ovr;
  bool  sel23 = false, g3f = false;
  if (isP) {
    const bool g2 = (g == 2);
    g3f   = (g == 3);
    sel23 = g2 | g3f;
    zero4[0]=0.f; zero4[1]=0.f; zero4[2]=0.f; zero4[3]=0.f;
    ovr = zero4; if (g2) ovr[0] = 1.0f;    // bias rider at k=20
#pragma unroll
    for (int ni = 0; ni < 4; ++ni) {
      const int hhh = hh * 64 + ni * 16 + r;
      float wv[8];
#pragma unroll
      for (int j = 0; j < 8; ++j) {
        const int k = 8 * g + j;
        wv[j] = (k < Ddim) ? W1[hhh * Ddim + k] : ((k == Ddim) ? b1[hhh] : 0.0f);
      }
#pragma unroll
      for (int d = 0; d < 4; ++d) {
        const uint32_t u0 = __float_as_uint(wv[2*d]), u1 = __float_as_uint(wv[2*d+1]);
        const uint32_t h0 = (u0 + 0x8000u) & 0xFFFF0000u;
        const uint32_t h1 = (u1 + 0x8000u) & 0xFFFF0000u;
        bhi[ni][d] = (int)(h1 | (h0 >> 16));
        const float l0 = wv[2*d]   - __uint_as_float(h0);
        const float l1 = wv[2*d+1] - __uint_as_float(h1);
        const uint32_t e0 = (__float_as_uint(l0) + 0x8000u) & 0xFFFF0000u;
        const uint32_t e1 = (__float_as_uint(l1) + 0x8000u) & 0xFFFF0000u;
        blo[ni][d] = (int)(e1 | (e0 >> 16));
      }
    }
  }

  // ---------------- scanner-only state (lanes >=32 duplicate lane l&31) ----------------
  float    mem = 0.0f;
  bool     sp  = false;
  uint32_t cnt = 0u;
  f32x2    negT2; negT2[0] = -THR; negT2[1] = -THR;

  // chunk = 32 t x 20 d = 2560 B; each producer stages its 1280 B half
#define STAGE(CH, BUF) do {                                                            \
    const float* g0_ = xb + (CH) * 640 + pwid * 320 + l * 4;                           \
    char* lb_ = (char*)&xraw[0][0] + (BUF) * 2560 + pwid * 1280 + l * 16;              \
    const float* p0_ = g0_;  if (p0_ > clampMax) p0_ = clampMax;                       \
    __builtin_amdgcn_global_load_lds(                                                  \
      (const __attribute__((address_space(1))) unsigned int*)p0_,                      \
      (__attribute__((address_space(3))) unsigned int*)lb_, 16, 0, 0);                 \
    if (l < 16) {                                                                      \
      const float* p1_ = g0_ + 256;  if (p1_ > clampMax) p1_ = clampMax;               \
      __builtin_amdgcn_global_load_lds(                                                \
        (const __attribute__((address_space(1))) unsigned int*)p1_,                    \
        (__attribute__((address_space(3))) unsigned int*)(lb_ + 1024), 16, 0, 0);      \
    } } while (0)

#define VM0()  asm volatile("s_waitcnt vmcnt(0)" ::: "memory");
#define LGW(N) asm volatile("s_waitcnt lgkmcnt(" #N ")" ::: "memory"); __builtin_amdgcn_sched_barrier(0);
#define BAR()  __builtin_amdgcn_sched_barrier(0); __builtin_amdgcn_s_barrier(); __builtin_amdgcn_sched_barrier(0);

#define SELA(A0, A1) { A0 = g3f ? zero4 : A0;  A1 = sel23 ? ovr : A1; }
#define CVT8(AHI, ALO, A0, A1) {                                                       \
    uint32_t h_, lo_;                                                                  \
    CVT_HILO(h_, lo_, A0[0], A0[1]) AHI[0]=(int)h_; ALO[0]=(int)lo_;                   \
    CVT_HILO(h_, lo_, A0[2], A0[3]) AHI[1]=(int)h_; ALO[1]=(int)lo_;                   \
    CVT_HILO(h_, lo_, A1[0], A1[1]) AHI[2]=(int)h_; ALO[2]=(int)lo_;                   \
    CVT_HILO(h_, lo_, A1[2], A1[3]) AHI[3]=(int)h_; ALO[3]=(int)lo_; }

#define MM12(AHI, ALO, C0,C1,C2,C3)                                                    \
    MFMA0(C0, ALO, bhi[0]) MFMA0(C1, ALO, bhi[1])                                      \
    MFMA0(C2, ALO, bhi[2]) MFMA0(C3, ALO, bhi[3])                                      \
    MFMA (C0, AHI, blo[0]) MFMA (C1, AHI, blo[1])                                      \
    MFMA (C2, AHI, blo[2]) MFMA (C3, AHI, blo[3])                                      \
    MFMA (C0, AHI, bhi[0]) MFMA (C1, AHI, bhi[1])                                      \
    MFMA (C2, AHI, bhi[2]) MFMA (C3, AHI, bhi[3])

  // t-major C-writes, stride 66 dw: per ni, write2 pair covers t..t+3
#define CW2(NI, AC)                                                                    \
    asm volatile("ds_write2_b32 %0, %1, %2 offset0:%c3 offset1:%c4"                    \
                 :: "v"(cwb_),  "v"(AC[0]), "v"(AC[1]), "n"(16*(NI)), "n"(16*(NI)+66)); \
    asm volatile("ds_write2_b32 %0, %1, %2 offset0:%c3 offset1:%c4"                    \
                 :: "v"(cwb2_), "v"(AC[2]), "v"(AC[3]), "n"(16*(NI)), "n"(16*(NI)+66));

  // one 16-t tile (t_local = TLOC) -> 12 MFMA -> cur[pbuf]
#define GEMM1(TLOC) {                                                                  \
    const uint32_t afb_ = xrawB + (uint32_t)(pbuf * 2560 + (TLOC) * 80 + 80 * r + 32 * g); \
    f32x4 a0_, a1_;                                                                    \
    asm volatile("ds_read_b128 %0, %1 offset:0"  : "=v"(a0_) : "v"(afb_));             \
    asm volatile("ds_read_b128 %0, %1 offset:16" : "=v"(a1_) : "v"(afb_));             \
    LGW(0)                                                                             \
    SELA(a0_, a1_)                                                                     \
    i32x4 ahi_, alo_;  CVT8(ahi_, alo_, a0_, a1_)                                      \
    asm volatile("s_nop 2");                                                           \
    f32x4 c0_, c1_, c2_, c3_;                                                          \
    MM12(ahi_, alo_, c0_, c1_, c2_, c3_)                                               \
    asm volatile("s_nop 7"); asm volatile("s_nop 4");                                  \
    const uint32_t cwb_  = curB + (uint32_t)(pbuf * 8448 + 264 * ((TLOC) + 4 * g) + 4 * r); \
    const uint32_t cwb2_ = cwb_ + 528u;                                                \
    CW2(0, c0_) CW2(1, c1_) CW2(2, c2_) CW2(3, c3_) }

  // ---- scanner: ring-8 read2; one counted wait per 4 timesteps ----
#define RD2A(PR, AD) asm volatile("ds_read2_b32 %0, %1 offset0:0 offset1:66" : "=v"(PR) : "v"(AD));
#define CONSUME(PR) {                                                                  \
    f32x2 cm_; asm("v_pk_add_f32 %0, %1, %2" : "=v"(cm_) : "v"(PR), "v"(negT2));       \
    float mP_ = fmaf(BETA, mem, PR[0]);                                                \
    float mM_ = fmaf(BETA, mem, cm_[0]);                                               \
    mem = sp ? mM_ : mP_;                                                              \
    sp  = mem > THR;                                                                   \
    cnt += sp ? 1u : 0u;                                                               \
    mP_ = fmaf(BETA, mem, PR[1]);                                                      \
    mM_ = fmaf(BETA, mem, cm_[1]);                                                     \
    mem = sp ? mM_ : mP_;                                                              \
    sp  = mem > THR;                                                                   \
    cnt += sp ? 1u : 0u; }

  // slot s covers t = 2s, 2s+1 at byte addr spB + s*528
#define SFI(RGA, RGB, SA, SB) { LGW(6) CONSUME(pr##RGA) CONSUME(pr##RGB)               \
    { const uint32_t adA_ = spB + (uint32_t)((SA) * 528); RD2A(pr##RGA, adA_) }        \
    { const uint32_t adB_ = spB + (uint32_t)((SB) * 528); RD2A(pr##RGB, adB_) } }
#define SFT(RGA, RGB, W) { LGW(W) CONSUME(pr##RGA) CONSUME(pr##RGB) }

#define SCAN_PRE()                                                                     \
    f32x2 pr0, pr1, pr2, pr3, pr4, pr5, pr6, pr7;                                      \
    RD2A(pr0, spB)          RD2A(pr1, spB + 528u)   RD2A(pr2, spB + 1056u)             \
    RD2A(pr3, spB + 1584u)  RD2A(pr4, spB + 2112u)  RD2A(pr5, spB + 2640u)             \
    RD2A(pr6, spB + 3168u)  RD2A(pr7, spB + 3696u)

#define SCAN_FULL() {   /* 16 slots = 32 t */                                          \
    SCAN_PRE()                                                                         \
    SFI(0,1,  8, 9) SFI(2,3, 10,11) SFI(4,5, 12,13) SFI(6,7, 14,15)                    \
    SFT(0,1,6) SFT(2,3,4) SFT(4,5,2) SFT(6,7,0) }

#define SCAN_TAIL() {   /* 8 slots = 16 t */                                           \
    SCAN_PRE()                                                                         \
    SFT(0,1,6) SFT(2,3,4) SFT(4,5,2) SFT(6,7,0) }

  const uint32_t spB0 = curB + (uint32_t)((swid * 32 + (l & 31)) * 4);

  // ================= main phase loop: 64 phases =================
  if (isP) STAGE(0, 0);

#pragma unroll 1
  for (int ph = 0; ph <= NCHF + 1; ++ph) {
    if (isP) {
      if (ph <= NCHF) {
        VM0()
        if (ph < NCHF) STAGE(ph + 1, (ph + 1) & 1);
        const uint32_t pbuf = (uint32_t)(ph & 1);
        if (ph < NCHF) {
          GEMM1(pwid * 16)
        } else if (pwid == 0) {       // tail chunk 62: 16 t in producer-0 half
          GEMM1(0)
        }
        LGW(0)                        // cur writes retired
      }
    } else {
      if (ph >= 1) {
        const uint32_t spB = spB0 + (uint32_t)(((ph - 1) & 1) * 8448);
        if (ph - 1 < NCHF) { SCAN_FULL() }
        else               { SCAN_TAIL() }
      }
    }
    BAR()
  }

  if (!isP && l < 32) cnt_s[swid * 32 + (l & 31)] = (float)cnt;
  __syncthreads();

  // ---- epilogue: 64-h partial logits, atomically accumulated into out ----
  if (tid < Cdim) {
    float dot = 0.0f;
#pragma unroll
    for (int k = 0; k < 64; ++k)
      dot = fmaf(cnt_s[k], W2[tid * Hdim + hh * 64 + k], dot);
    const float Tf = (float)Tdim;
    const float scale = 1.0f / Tf + 0.1f / (Tf + 1e-6f);
    float val = dot * scale + (hh == 0 ? 1.1f * b2[tid] : 0.0f);
    atomicAdd(&out[bb * Cdim + tid], val);
  }
}

extern "C" void kernel_launch(void* const* d_in, const int* in_sizes, int n_in,
                              void* d_out, int out_size, void* d_ws, size_t ws_size,
                              hipStream_t stream) {
  const float* x  = (const float*)d_in[0];
  const float* W1 = (const float*)d_in[1];
  const float* b1 = (const float*)d_in[2];
  const float* W2 = (const float*)d_in[3];
  const float* b2 = (const float*)d_in[4];
  float* out = (float*)d_out;

  hipMemsetAsync(out, 0, (size_t)Bdim * Cdim * sizeof(float), stream);
  snn_spec5_kernel<<<dim3(Bdim * 2), dim3(256), 0, stream>>>(x, W1, b1, W2, b2, out);
}